// Round 4
// baseline (404.876 us; speedup 1.0000x reference)
//
#include <hip/hip_runtime.h>

typedef __bf16 bf16x8 __attribute__((ext_vector_type(8)));
typedef float f32x4 __attribute__((ext_vector_type(4)));
typedef short short4v __attribute__((ext_vector_type(4)));
typedef unsigned short ushort8 __attribute__((ext_vector_type(8)));
typedef unsigned int uint4v __attribute__((ext_vector_type(4)));

#define AS1 __attribute__((address_space(1)))
#define AS3 __attribute__((address_space(3)))
#define GLL16(g, l) __builtin_amdgcn_global_load_lds((const AS1 void*)(g), (AS3 void*)(l), 16, 0, 0)
#define MFMA16(a, b, c) __builtin_amdgcn_mfma_f32_16x16x32_bf16((a), (b), (c), 0, 0, 0)
#define L2E 1.44269504f

__device__ __forceinline__ unsigned short f2bf(float f) {
  unsigned int u = __builtin_bit_cast(unsigned int, f);
  u = (u + 0x7fffu + ((u >> 16) & 1u)) >> 16;
  return (unsigned short)u;
}

__device__ __forceinline__ unsigned int cvtpk_bf16(float lo, float hi) {
  unsigned int r;
  asm("v_cvt_pk_bf16_f32 %0, %1, %2" : "=v"(r) : "v"(lo), "v"(hi));
  return r;
}

// ---------------- convert: f32 -> bf16 (x, concat weights, w_o) ----------------
__global__ void convert_kernel(const float* __restrict__ x,
                               const float* __restrict__ w_qt, const float* __restrict__ w_kt,
                               const float* __restrict__ w_qs, const float* __restrict__ w_ks,
                               const float* __restrict__ w_v, const float* __restrict__ w_o,
                               unsigned short* __restrict__ xb, unsigned short* __restrict__ wcat,
                               unsigned short* __restrict__ wob) {
  const int NX = 4096 * 1024, NW = 3072 * 1024, NO = 1024 * 1024;
  int stride = gridDim.x * blockDim.x;
  for (int i = blockIdx.x * blockDim.x + threadIdx.x; i < NX + NW + NO; i += stride) {
    if (i < NX) {
      xb[i] = f2bf(x[i]);
    } else if (i < NX + NW) {
      int j = i - NX;
      int n = j >> 10, k = j & 1023;
      const float* src;
      if (n < 256)        src = w_qt + n * 1024;
      else if (n < 1024)  src = w_qs + (n - 256) * 1024;
      else if (n < 1280)  src = w_kt + (n - 1024) * 1024;
      else if (n < 2048)  src = w_ks + (n - 1280) * 1024;
      else                src = w_v + (n - 2048) * 1024;
      wcat[j] = f2bf(src[k]);
    } else {
      int j = i - NX - NW;
      wob[j] = f2bf(w_o[j]);
    }
  }
}

// ---------------- GEMM 1: X(4096x1024) * Wcat(3072x1024)^T -> Q,K,Vt ----------------
__global__ __launch_bounds__(256) void gemm_qkv(const unsigned short* __restrict__ A,
                                                const unsigned short* __restrict__ Bw,
                                                unsigned short* __restrict__ qb,
                                                unsigned short* __restrict__ kb,
                                                unsigned short* __restrict__ vt) {
  __shared__ unsigned short As[128 * 32];
  __shared__ unsigned short Bs[128 * 32];
  const int t = threadIdx.x;
  const int lane = t & 63, wid = t >> 6;
  const int wm = wid >> 1, wn = wid & 1;
  const int lr = lane & 15, lg = lane >> 4;
  const int m0 = blockIdx.x * 128, n0 = blockIdx.y * 128;
  const int K = 1024;
  f32x4 acc[4][4] = {};
  const unsigned short* gA0 = A + (m0 + (t >> 2)) * K + (t & 3) * 8;
  const unsigned short* gB0 = Bw + (n0 + (t >> 2)) * K + (t & 3) * 8;
  char* lA = (char*)As + wid * 1024;
  char* lB = (char*)Bs + wid * 1024;
  for (int k0 = 0; k0 < K; k0 += 32) {
    __syncthreads();
    GLL16(gA0 + k0, lA);
    GLL16(gA0 + 64 * K + k0, lA + 4096);
    GLL16(gB0 + k0, lB);
    GLL16(gB0 + 64 * K + k0, lB + 4096);
    __syncthreads();
    bf16x8 af[4], bfr[4];
#pragma unroll
    for (int i = 0; i < 4; ++i) {
      af[i] = *(const bf16x8*)&As[(wm * 64 + i * 16 + lr) * 32 + lg * 8];
      bfr[i] = *(const bf16x8*)&Bs[(wn * 64 + i * 16 + lr) * 32 + lg * 8];
    }
#pragma unroll
    for (int i = 0; i < 4; ++i)
#pragma unroll
      for (int j = 0; j < 4; ++j)
        acc[i][j] = MFMA16(af[i], bfr[j], acc[i][j]);
  }
  // epilogue: scatter into Q (B,H,L,64), K (B,H,L,64), Vt (B,H,64,L)
#pragma unroll
  for (int i = 0; i < 4; ++i) {
#pragma unroll
    for (int j = 0; j < 4; ++j) {
      int n = n0 + wn * 64 + j * 16 + lr;
      int mb = m0 + wm * 64 + i * 16 + lg * 4;
      f32x4 v = acc[i][j];
      if (n < 2048) {
        unsigned short* dst = (n < 1024) ? qb : kb;
        int nn = n & 1023;
        int h = nn >> 6, d = nn & 63;
#pragma unroll
        for (int r = 0; r < 4; ++r) {
          int m = mb + r;
          int b = m >> 11, l = m & 2047;
          dst[((b * 16 + h) * 2048 + l) * 64 + d] = f2bf(v[r]);
        }
      } else {
        int nn = n - 2048;
        int h = nn >> 6, d = nn & 63;
        int b = mb >> 11, l = mb & 2047;
        short4v pk;
        pk[0] = (short)f2bf(v[0]); pk[1] = (short)f2bf(v[1]);
        pk[2] = (short)f2bf(v[2]); pk[3] = (short)f2bf(v[3]);
        *(short4v*)&vt[((b * 16 + h) * 64 + d) * 2048 + l] = pk;
      }
    }
  }
}

// ---------------- attn pass A: rowsums -> rws = -log2(rowsum) ----------------
// Block: 64 q-rows, 4 waves; wave w owns k-slice [w*512, w*512+512).
__global__ __launch_bounds__(256, 4) void attn_rowsum(const unsigned short* __restrict__ qb,
                                                      const unsigned short* __restrict__ kb,
                                                      const float* __restrict__ mask,
                                                      const float* __restrict__ w_sigma,
                                                      float* __restrict__ rws) {
  __shared__ float psum[4][64];
  const int t = threadIdx.x;
  const int lane = t & 63, w = t >> 6;
  const int lr = lane & 15, lg = lane >> 4;
  const int q0 = blockIdx.x * 64;
  const int bh = blockIdx.y;
  const int b = bh >> 4, h = bh & 15;
  const float sigma = 1.0f / (1.0f + __expf(-w_sigma[0]));
  const float fac2 = ((h < 4) ? (-sigma * 0.125f) : 0.125f) * L2E;
  const float* maskb = mask + b * 2048;
  const int kbase = w * 512;

  bf16x8 aq[4][2];
#pragma unroll
  for (int qt = 0; qt < 4; ++qt) {
    const unsigned short* qp = qb + ((bh * 2048) + q0 + qt * 16 + lr) * 64 + lg * 8;
    aq[qt][0] = *(const bf16x8*)qp;
    aq[qt][1] = *(const bf16x8*)(qp + 32);
  }

  float rs[4][4] = {};
  for (int c = 0; c < 16; ++c) {
    int kc = kbase + c * 32;
#pragma unroll
    for (int kt = 0; kt < 2; ++kt) {
      int col = kc + kt * 16 + lr;
      const unsigned short* kp = kb + ((bh * 2048) + col) * 64 + lg * 8;
      bf16x8 b0 = *(const bf16x8*)kp;
      bf16x8 b1 = *(const bf16x8*)(kp + 32);
      float mv2 = maskb[col] * L2E;
#pragma unroll
      for (int qt = 0; qt < 4; ++qt) {
        f32x4 acc = {};
        acc = MFMA16(aq[qt][0], b0, acc);
        acc = MFMA16(aq[qt][1], b1, acc);
#pragma unroll
        for (int r = 0; r < 4; ++r) rs[qt][r] += exp2f(acc[r] * fac2 + mv2);
      }
    }
  }
#pragma unroll
  for (int o = 1; o < 16; o <<= 1)
#pragma unroll
    for (int qt = 0; qt < 4; ++qt)
#pragma unroll
      for (int r = 0; r < 4; ++r) rs[qt][r] += __shfl_xor(rs[qt][r], o);
  if (lr == 0) {
#pragma unroll
    for (int qt = 0; qt < 4; ++qt)
#pragma unroll
      for (int r = 0; r < 4; ++r) psum[w][qt * 16 + lg * 4 + r] = rs[qt][r];
  }
  __syncthreads();
  if (t < 64) {
    float s = psum[0][t] + psum[1][t] + psum[2][t] + psum[3][t];
    rws[bh * 2048 + q0 + t] = -log2f(s);
  }
}

// ---------------- attn pass B: normalized probs stream + PV ----------------
// Block: 32 q-rows, 4 waves; wave w owns k-slice [w*512, w*512+512).
__global__ __launch_bounds__(256, 4) void attn_main(const unsigned short* __restrict__ qb,
                                                    const unsigned short* __restrict__ kb,
                                                    const unsigned short* __restrict__ vt,
                                                    const float* __restrict__ mask,
                                                    const float* __restrict__ w_sigma,
                                                    const float* __restrict__ rws,
                                                    float* __restrict__ probs,
                                                    unsigned short* __restrict__ ao) {
  __shared__ __align__(16) char ebuf[4][4096];   // per-wave 32x32 f32 p-tile, XOR-swizzled
  __shared__ __align__(16) float pvacc[2048];    // 32 q x 64 d PV accumulator
  const int t = threadIdx.x;
  const int lane = t & 63, w = t >> 6;
  const int lr = lane & 15, lg = lane >> 4;
  const int q0 = blockIdx.x * 32;
  const int bh = blockIdx.y;
  const int b = bh >> 4, h = bh & 15;
  const float sigma = 1.0f / (1.0f + __expf(-w_sigma[0]));
  const float fac2 = ((h < 4) ? (-sigma * 0.125f) : 0.125f) * L2E;
  const float* maskb = mask + b * 2048;
  const int kbase = w * 512;

  for (int i = t; i < 2048; i += 256) pvacc[i] = 0.0f;
  __syncthreads();

  bf16x8 aq[2][2];
  float lr2[2][4];
#pragma unroll
  for (int qt = 0; qt < 2; ++qt) {
    const unsigned short* qp = qb + ((bh * 2048) + q0 + qt * 16 + lr) * 64 + lg * 8;
    aq[qt][0] = *(const bf16x8*)qp;
    aq[qt][1] = *(const bf16x8*)(qp + 32);
#pragma unroll
    for (int r = 0; r < 4; ++r)
      lr2[qt][r] = rws[bh * 2048 + q0 + qt * 16 + lg * 4 + r];
  }

  char* eb = ebuf[w];
  float* pp = probs + (long long)(bh * 2048 + q0) * 2048;
  f32x4 pv[2][4] = {};
  for (int c = 0; c < 16; ++c) {
    int kc = kbase + c * 32;
    // compute p = exp2(s*fac2 + mask*log2e - log2(rowsum)), stage f32 in LDS
#pragma unroll
    for (int kt = 0; kt < 2; ++kt) {
      int col = kc + kt * 16 + lr;
      const unsigned short* kp = kb + ((bh * 2048) + col) * 64 + lg * 8;
      bf16x8 b0 = *(const bf16x8*)kp;
      bf16x8 b1 = *(const bf16x8*)(kp + 32);
      float mv2 = maskb[col] * L2E;
#pragma unroll
      for (int qt = 0; qt < 2; ++qt) {
        f32x4 acc = {};
        acc = MFMA16(aq[qt][0], b0, acc);
        acc = MFMA16(aq[qt][1], b1, acc);
#pragma unroll
        for (int r = 0; r < 4; ++r) {
          int row = qt * 16 + lg * 4 + r;
          float p = exp2f(acc[r] * fac2 + mv2 + lr2[qt][r]);
          int off = (row * 128 + (kt * 16 + lr) * 4) ^ ((row & 7) << 4);
          *(float*)(eb + off) = p;
        }
      }
    }
    asm volatile("s_waitcnt lgkmcnt(0)" ::: "memory");
    // read back: same regs feed the coalesced probs store AND the PV A-fragment
    bf16x8 pa[2];
#pragma unroll
    for (int qt = 0; qt < 2; ++qt) {
      int row = qt * 16 + lr;
      int base = row * 128 + lg * 32;
      int sw = (row & 7) << 4;
      f32x4 v0 = *(const f32x4*)(eb + (base ^ sw));
      f32x4 v1 = *(const f32x4*)(eb + ((base + 16) ^ sw));
      float* dst = pp + row * 2048 + kc + lg * 8;
      __builtin_nontemporal_store(v0, (f32x4*)dst);
      __builtin_nontemporal_store(v1, (f32x4*)(dst + 4));
      uint4v u;
      u[0] = cvtpk_bf16(v0[0], v0[1]);
      u[1] = cvtpk_bf16(v0[2], v0[3]);
      u[2] = cvtpk_bf16(v1[0], v1[1]);
      u[3] = cvtpk_bf16(v1[2], v1[3]);
      pa[qt] = __builtin_bit_cast(bf16x8, u);
    }
#pragma unroll
    for (int dt = 0; dt < 4; ++dt) {
      const unsigned short* vp = vt + ((bh * 64) + dt * 16 + lr) * 2048 + kc + lg * 8;
      bf16x8 bv = *(const bf16x8*)vp;
      pv[0][dt] = MFMA16(pa[0], bv, pv[0][dt]);
      pv[1][dt] = MFMA16(pa[1], bv, pv[1][dt]);
    }
  }

  // merge PV partials across waves (p already normalized -> no final scale)
#pragma unroll
  for (int qt = 0; qt < 2; ++qt)
#pragma unroll
    for (int dt = 0; dt < 4; ++dt)
#pragma unroll
      for (int r = 0; r < 4; ++r)
        atomicAdd(&pvacc[(qt * 16 + lg * 4 + r) * 64 + dt * 16 + lr], pv[qt][dt][r]);
  __syncthreads();

  {
    int row = t >> 3, c8 = (t & 7) * 8;
    f32x4 v0 = *(const f32x4*)&pvacc[row * 64 + c8];
    f32x4 v1 = *(const f32x4*)&pvacc[row * 64 + c8 + 4];
    ushort8 o;
#pragma unroll
    for (int i = 0; i < 4; ++i) {
      o[i] = f2bf(v0[i]);
      o[i + 4] = f2bf(v1[i]);
    }
    *(ushort8*)&ao[((b * 2048) + q0 + row) * 1024 + h * 64 + c8] = o;
  }
}

// ---------------- GEMM 2: AO(4096x1024) * Wo(1024x1024)^T -> out f32 ----------------
__global__ __launch_bounds__(256) void gemm_oproj(const unsigned short* __restrict__ A,
                                                  const unsigned short* __restrict__ Bw,
                                                  float* __restrict__ out) {
  __shared__ unsigned short As[128 * 32];
  __shared__ unsigned short Bs[128 * 32];
  const int t = threadIdx.x;
  const int lane = t & 63, wid = t >> 6;
  const int wm = wid >> 1, wn = wid & 1;
  const int lr = lane & 15, lg = lane >> 4;
  const int m0 = blockIdx.x * 128, n0 = blockIdx.y * 128;
  const int K = 1024;
  f32x4 acc[4][4] = {};
  const unsigned short* gA0 = A + (m0 + (t >> 2)) * K + (t & 3) * 8;
  const unsigned short* gB0 = Bw + (n0 + (t >> 2)) * K + (t & 3) * 8;
  char* lA = (char*)As + wid * 1024;
  char* lB = (char*)Bs + wid * 1024;
  for (int k0 = 0; k0 < K; k0 += 32) {
    __syncthreads();
    GLL16(gA0 + k0, lA);
    GLL16(gA0 + 64 * K + k0, lA + 4096);
    GLL16(gB0 + k0, lB);
    GLL16(gB0 + 64 * K + k0, lB + 4096);
    __syncthreads();
    bf16x8 af[4], bfr[4];
#pragma unroll
    for (int i = 0; i < 4; ++i) {
      af[i] = *(const bf16x8*)&As[(wm * 64 + i * 16 + lr) * 32 + lg * 8];
      bfr[i] = *(const bf16x8*)&Bs[(wn * 64 + i * 16 + lr) * 32 + lg * 8];
    }
#pragma unroll
    for (int i = 0; i < 4; ++i)
#pragma unroll
      for (int j = 0; j < 4; ++j)
        acc[i][j] = MFMA16(af[i], bfr[j], acc[i][j]);
  }
#pragma unroll
  for (int i = 0; i < 4; ++i) {
#pragma unroll
    for (int j = 0; j < 4; ++j) {
      int n = n0 + wn * 64 + j * 16 + lr;
      int mb = m0 + wm * 64 + i * 16 + lg * 4;
#pragma unroll
      for (int r = 0; r < 4; ++r)
        out[(mb + r) * 1024 + n] = acc[i][j][r];
    }
  }
}

extern "C" void kernel_launch(void* const* d_in, const int* in_sizes, int n_in,
                              void* d_out, int out_size, void* d_ws, size_t ws_size,
                              hipStream_t stream) {
  const float* x       = (const float*)d_in[0];
  const float* amask   = (const float*)d_in[1];
  const float* w_qt    = (const float*)d_in[2];
  const float* w_kt    = (const float*)d_in[3];
  const float* w_qs    = (const float*)d_in[4];
  const float* w_ks    = (const float*)d_in[5];
  const float* w_sigma = (const float*)d_in[6];
  const float* w_v     = (const float*)d_in[7];
  const float* w_o     = (const float*)d_in[8];

  char* ws = (char*)d_ws;
  unsigned short* xb   = (unsigned short*)ws;                    // 8 MB
  unsigned short* wcat = (unsigned short*)(ws + 8388608);        // 6 MB
  unsigned short* wob  = (unsigned short*)(ws + 14680064);       // 2 MB
  unsigned short* qb   = (unsigned short*)(ws + 16777216);       // 8 MB
  unsigned short* kb   = (unsigned short*)(ws + 25165824);       // 8 MB
  unsigned short* vt   = (unsigned short*)(ws + 33554432);       // 8 MB
  unsigned short* ao   = (unsigned short*)(ws + 41943040);       // 8 MB
  float* rws           = (float*)(ws + 50331648);                // 256 KB

  float* outp = (float*)d_out;
  float* probs = outp + 4194304;

  convert_kernel<<<2048, 256, 0, stream>>>(x, w_qt, w_kt, w_qs, w_ks, w_v, w_o, xb, wcat, wob);
  gemm_qkv<<<dim3(32, 24), 256, 0, stream>>>(xb, wcat, qb, kb, vt);
  attn_rowsum<<<dim3(32, 32), 256, 0, stream>>>(qb, kb, amask, w_sigma, rws);
  attn_main<<<dim3(64, 32), 256, 0, stream>>>(qb, kb, vt, amask, w_sigma, rws, probs, ao);
  gemm_oproj<<<dim3(32, 8), 256, 0, stream>>>(ao, wob, outp);
}

// Round 5
// 348.451 us; speedup vs baseline: 1.1619x; 1.1619x over previous
//
#include <hip/hip_runtime.h>

typedef __bf16 bf16x8 __attribute__((ext_vector_type(8)));
typedef float f32x4 __attribute__((ext_vector_type(4)));
typedef float f32x16 __attribute__((ext_vector_type(16)));
typedef short short4v __attribute__((ext_vector_type(4)));
typedef unsigned short ushort8 __attribute__((ext_vector_type(8)));

#define AS1 __attribute__((address_space(1)))
#define AS3 __attribute__((address_space(3)))
#define GLL16(g, l) __builtin_amdgcn_global_load_lds((const AS1 void*)(g), (AS3 void*)(l), 16, 0, 0)
#define MFMA16(a, b, c) __builtin_amdgcn_mfma_f32_16x16x32_bf16((a), (b), (c), 0, 0, 0)
#define MFMA32(a, b, c) __builtin_amdgcn_mfma_f32_32x32x16_bf16((a), (b), (c), 0, 0, 0)
#define L2E 1.44269504f

__device__ __forceinline__ unsigned short f2bf(float f) {
  unsigned int u = __builtin_bit_cast(unsigned int, f);
  u = (u + 0x7fffu + ((u >> 16) & 1u)) >> 16;
  return (unsigned short)u;
}

// ---------------- convert: f32 -> bf16 (x, concat weights, w_o) ----------------
__global__ void convert_kernel(const float* __restrict__ x,
                               const float* __restrict__ w_qt, const float* __restrict__ w_kt,
                               const float* __restrict__ w_qs, const float* __restrict__ w_ks,
                               const float* __restrict__ w_v, const float* __restrict__ w_o,
                               unsigned short* __restrict__ xb, unsigned short* __restrict__ wcat,
                               unsigned short* __restrict__ wob) {
  const int NX = 4096 * 1024, NW = 3072 * 1024, NO = 1024 * 1024;
  int stride = gridDim.x * blockDim.x;
  for (int i = blockIdx.x * blockDim.x + threadIdx.x; i < NX + NW + NO; i += stride) {
    if (i < NX) {
      xb[i] = f2bf(x[i]);
    } else if (i < NX + NW) {
      int j = i - NX;
      int n = j >> 10, k = j & 1023;
      const float* src;
      if (n < 256)        src = w_qt + n * 1024;
      else if (n < 1024)  src = w_qs + (n - 256) * 1024;
      else if (n < 1280)  src = w_kt + (n - 1024) * 1024;
      else if (n < 2048)  src = w_ks + (n - 1280) * 1024;
      else                src = w_v + (n - 2048) * 1024;
      wcat[j] = f2bf(src[k]);
    } else {
      int j = i - NX - NW;
      wob[j] = f2bf(w_o[j]);
    }
  }
}

// ---------------- GEMM 1: X(4096x1024) * Wcat(3072x1024)^T -> Q,K,Vt ----------------
__global__ __launch_bounds__(256) void gemm_qkv(const unsigned short* __restrict__ A,
                                                const unsigned short* __restrict__ Bw,
                                                unsigned short* __restrict__ qb,
                                                unsigned short* __restrict__ kb,
                                                unsigned short* __restrict__ vt) {
  __shared__ unsigned short As[128 * 32];
  __shared__ unsigned short Bs[128 * 32];
  const int t = threadIdx.x;
  const int lane = t & 63, wid = t >> 6;
  const int wm = wid >> 1, wn = wid & 1;
  const int lr = lane & 15, lg = lane >> 4;
  const int m0 = blockIdx.x * 128, n0 = blockIdx.y * 128;
  const int K = 1024;
  f32x4 acc[4][4] = {};
  const unsigned short* gA0 = A + (m0 + (t >> 2)) * K + (t & 3) * 8;
  const unsigned short* gB0 = Bw + (n0 + (t >> 2)) * K + (t & 3) * 8;
  char* lA = (char*)As + wid * 1024;
  char* lB = (char*)Bs + wid * 1024;
  for (int k0 = 0; k0 < K; k0 += 32) {
    __syncthreads();
    GLL16(gA0 + k0, lA);
    GLL16(gA0 + 64 * K + k0, lA + 4096);
    GLL16(gB0 + k0, lB);
    GLL16(gB0 + 64 * K + k0, lB + 4096);
    __syncthreads();
    bf16x8 af[4], bfr[4];
#pragma unroll
    for (int i = 0; i < 4; ++i) {
      af[i] = *(const bf16x8*)&As[(wm * 64 + i * 16 + lr) * 32 + lg * 8];
      bfr[i] = *(const bf16x8*)&Bs[(wn * 64 + i * 16 + lr) * 32 + lg * 8];
    }
#pragma unroll
    for (int i = 0; i < 4; ++i)
#pragma unroll
      for (int j = 0; j < 4; ++j)
        acc[i][j] = MFMA16(af[i], bfr[j], acc[i][j]);
  }
  // epilogue: scatter into Q (B,H,L,64), K (B,H,L,64), Vt (B,H,64,L)
#pragma unroll
  for (int i = 0; i < 4; ++i) {
#pragma unroll
    for (int j = 0; j < 4; ++j) {
      int n = n0 + wn * 64 + j * 16 + lr;
      int mb = m0 + wm * 64 + i * 16 + lg * 4;
      f32x4 v = acc[i][j];
      if (n < 2048) {
        unsigned short* dst = (n < 1024) ? qb : kb;
        int nn = n & 1023;
        int h = nn >> 6, d = nn & 63;
#pragma unroll
        for (int r = 0; r < 4; ++r) {
          int m = mb + r;
          int b = m >> 11, l = m & 2047;
          dst[((b * 16 + h) * 2048 + l) * 64 + d] = f2bf(v[r]);
        }
      } else {
        int nn = n - 2048;
        int h = nn >> 6, d = nn & 63;
        int b = mb >> 11, l = mb & 2047;
        short4v pk;
        pk[0] = (short)f2bf(v[0]); pk[1] = (short)f2bf(v[1]);
        pk[2] = (short)f2bf(v[2]); pk[3] = (short)f2bf(v[3]);
        *(short4v*)&vt[((b * 16 + h) * 64 + d) * 2048 + l] = pk;
      }
    }
  }
}

// ---------------- attention: merged rowsum + normalized probs stream + PV ----------------
// Block: 32 q-rows, 4 waves; wave w owns k-slice [w*512, w*512+512).
// 32x32x16 MFMA; probs stored DIRECTLY from accumulator (col=lane&31 -> 128B segs).
__global__ __launch_bounds__(256, 3) void attn_kernel(const unsigned short* __restrict__ qb,
                                                      const unsigned short* __restrict__ kb,
                                                      const unsigned short* __restrict__ vt,
                                                      const float* __restrict__ mask,
                                                      const float* __restrict__ w_sigma,
                                                      float* __restrict__ probs,
                                                      unsigned short* __restrict__ ao) {
  __shared__ __align__(16) char plds[4][2048];   // per-wave 32x32 bf16 P-tile, XOR-swizzled
  __shared__ __align__(16) float pvacc[2048];    // 32 q x 64 d PV accumulator
  __shared__ float psum[4][32];
  __shared__ float rsum[32];
  const int t = threadIdx.x;
  const int lane = t & 63, w = t >> 6;
  const int col = lane & 31;          // k-col (S) / d-col (O)
  const int hi = lane >> 5;
  const int koff = hi * 8;
  const int q0 = blockIdx.x * 32;
  const int bh = blockIdx.y;
  const int b = bh >> 4, h = bh & 15;
  const float sigma = 1.0f / (1.0f + __expf(-w_sigma[0]));
  const float fac2 = ((h < 4) ? (-sigma * 0.125f) : 0.125f) * L2E;
  const float* maskb = mask + b * 2048;
  const int kbase = w * 512;

  for (int i = t; i < 2048; i += 256) pvacc[i] = 0.0f;

  // Q fragments: A-operand row=lane&31, k(d)=koff+i; 4 frags cover d=0..63
  bf16x8 qf[4];
  const unsigned short* qp = qb + (size_t)(bh * 2048 + q0 + col) * 64 + koff;
#pragma unroll
  for (int m = 0; m < 4; ++m) qf[m] = *(const bf16x8*)(qp + m * 16);

  // ---- pass 1: rowsums ----
  float rs[16];
#pragma unroll
  for (int r = 0; r < 16; ++r) rs[r] = 0.0f;
  for (int c = 0; c < 16; ++c) {
    int kc = kbase + c * 32;
    const unsigned short* kp = kb + (size_t)(bh * 2048 + kc + col) * 64 + koff;
    f32x16 s = {};
#pragma unroll
    for (int m = 0; m < 4; ++m) s = MFMA32(qf[m], *(const bf16x8*)(kp + m * 16), s);
    float mv2 = maskb[kc + col] * L2E;
#pragma unroll
    for (int r = 0; r < 16; ++r) rs[r] += exp2f(s[r] * fac2 + mv2);
  }
#pragma unroll
  for (int o = 1; o < 32; o <<= 1)
#pragma unroll
    for (int r = 0; r < 16; ++r) rs[r] += __shfl_xor(rs[r], o);
  if (col == 0) {
#pragma unroll
    for (int r = 0; r < 16; ++r) psum[w][(r & 3) + 8 * (r >> 2) + 4 * hi] = rs[r];
  }
  __syncthreads();
  if (t < 32) rsum[t] = -log2f(psum[0][t] + psum[1][t] + psum[2][t] + psum[3][t]);
  __syncthreads();

  float rws_l[16];
#pragma unroll
  for (int r = 0; r < 16; ++r) rws_l[r] = rsum[(r & 3) + 8 * (r >> 2) + 4 * hi];

  // ---- pass 2: recompute, stream normalized probs from acc, PV ----
  char* pl = plds[w];
  float* pp = probs + (size_t)(bh * 2048 + q0) * 2048;
  f32x16 oacc[2] = {};
  for (int c = 0; c < 16; ++c) {
    int kc = kbase + c * 32;
    const unsigned short* kp = kb + (size_t)(bh * 2048 + kc + col) * 64 + koff;
    f32x16 s = {};
#pragma unroll
    for (int m = 0; m < 4; ++m) s = MFMA32(qf[m], *(const bf16x8*)(kp + m * 16), s);
    float mv2 = maskb[kc + col] * L2E;
    float p[16];
#pragma unroll
    for (int r = 0; r < 16; ++r) p[r] = exp2f(s[r] * fac2 + (rws_l[r] + mv2));
    // probs: one nt dword store per reg = two 128B segments
    float* pr = pp + kc + col;
#pragma unroll
    for (int r = 0; r < 16; ++r) {
      int row = (r & 3) + 8 * (r >> 2) + 4 * hi;
      __builtin_nontemporal_store(p[r], pr + row * 2048);
    }
    // P -> bf16 LDS (own-wave tile only; no cross-wave sync needed)
#pragma unroll
    for (int r = 0; r < 16; ++r) {
      int row = (r & 3) + 8 * (r >> 2) + 4 * hi;
      int off = (row * 64 + col * 2) ^ ((row & 7) << 4);
      *(unsigned short*)(pl + off) = f2bf(p[r]);
    }
    asm volatile("" ::: "memory");  // compiler barrier: keep ds_reads after ds_writes
    // PV: O[32q x 64d] += P(32x32) * V(32k x 64d)
#pragma unroll
    for (int kh = 0; kh < 2; ++kh) {
      int arow = col;  // A row = q = lane&31
      int aoff = (arow * 64 + (kh * 16 + koff) * 2) ^ ((arow & 7) << 4);
      bf16x8 pa = *(const bf16x8*)(pl + aoff);
#pragma unroll
      for (int dh = 0; dh < 2; ++dh) {
        const unsigned short* vp = vt + (size_t)(bh * 64 + dh * 32 + col) * 2048 + kc + kh * 16 + koff;
        oacc[dh] = MFMA32(pa, *(const bf16x8*)vp, oacc[dh]);
      }
    }
  }

  // merge PV partials across waves
#pragma unroll
  for (int dh = 0; dh < 2; ++dh)
#pragma unroll
    for (int r = 0; r < 16; ++r) {
      int row = (r & 3) + 8 * (r >> 2) + 4 * hi;
      atomicAdd(&pvacc[row * 64 + dh * 32 + col], oacc[dh][r]);
    }
  __syncthreads();

  {
    int row = t >> 3, c8 = (t & 7) * 8;
    f32x4 v0 = *(const f32x4*)&pvacc[row * 64 + c8];
    f32x4 v1 = *(const f32x4*)&pvacc[row * 64 + c8 + 4];
    ushort8 o;
#pragma unroll
    for (int i = 0; i < 4; ++i) {
      o[i] = f2bf(v0[i]);
      o[i + 4] = f2bf(v1[i]);
    }
    *(ushort8*)&ao[((b * 2048) + q0 + row) * 1024 + h * 64 + c8] = o;
  }
}

// ---------------- GEMM 2: AO(4096x1024) * Wo(1024x1024)^T -> out f32 ----------------
__global__ __launch_bounds__(256) void gemm_oproj(const unsigned short* __restrict__ A,
                                                  const unsigned short* __restrict__ Bw,
                                                  float* __restrict__ out) {
  __shared__ unsigned short As[128 * 32];
  __shared__ unsigned short Bs[128 * 32];
  const int t = threadIdx.x;
  const int lane = t & 63, wid = t >> 6;
  const int wm = wid >> 1, wn = wid & 1;
  const int lr = lane & 15, lg = lane >> 4;
  const int m0 = blockIdx.x * 128, n0 = blockIdx.y * 128;
  const int K = 1024;
  f32x4 acc[4][4] = {};
  const unsigned short* gA0 = A + (m0 + (t >> 2)) * K + (t & 3) * 8;
  const unsigned short* gB0 = Bw + (n0 + (t >> 2)) * K + (t & 3) * 8;
  char* lA = (char*)As + wid * 1024;
  char* lB = (char*)Bs + wid * 1024;
  for (int k0 = 0; k0 < K; k0 += 32) {
    __syncthreads();
    GLL16(gA0 + k0, lA);
    GLL16(gA0 + 64 * K + k0, lA + 4096);
    GLL16(gB0 + k0, lB);
    GLL16(gB0 + 64 * K + k0, lB + 4096);
    __syncthreads();
    bf16x8 af[4], bfr[4];
#pragma unroll
    for (int i = 0; i < 4; ++i) {
      af[i] = *(const bf16x8*)&As[(wm * 64 + i * 16 + lr) * 32 + lg * 8];
      bfr[i] = *(const bf16x8*)&Bs[(wn * 64 + i * 16 + lr) * 32 + lg * 8];
    }
#pragma unroll
    for (int i = 0; i < 4; ++i)
#pragma unroll
      for (int j = 0; j < 4; ++j)
        acc[i][j] = MFMA16(af[i], bfr[j], acc[i][j]);
  }
#pragma unroll
  for (int i = 0; i < 4; ++i) {
#pragma unroll
    for (int j = 0; j < 4; ++j) {
      int n = n0 + wn * 64 + j * 16 + lr;
      int mb = m0 + wm * 64 + i * 16 + lg * 4;
#pragma unroll
      for (int r = 0; r < 4; ++r)
        out[(mb + r) * 1024 + n] = acc[i][j][r];
    }
  }
}

extern "C" void kernel_launch(void* const* d_in, const int* in_sizes, int n_in,
                              void* d_out, int out_size, void* d_ws, size_t ws_size,
                              hipStream_t stream) {
  const float* x       = (const float*)d_in[0];
  const float* amask   = (const float*)d_in[1];
  const float* w_qt    = (const float*)d_in[2];
  const float* w_kt    = (const float*)d_in[3];
  const float* w_qs    = (const float*)d_in[4];
  const float* w_ks    = (const float*)d_in[5];
  const float* w_sigma = (const float*)d_in[6];
  const float* w_v     = (const float*)d_in[7];
  const float* w_o     = (const float*)d_in[8];

  char* ws = (char*)d_ws;
  unsigned short* xb   = (unsigned short*)ws;                    // 8 MB
  unsigned short* wcat = (unsigned short*)(ws + 8388608);        // 6 MB
  unsigned short* wob  = (unsigned short*)(ws + 14680064);       // 2 MB
  unsigned short* qb   = (unsigned short*)(ws + 16777216);       // 8 MB
  unsigned short* kb   = (unsigned short*)(ws + 25165824);       // 8 MB
  unsigned short* vt   = (unsigned short*)(ws + 33554432);       // 8 MB
  unsigned short* ao   = (unsigned short*)(ws + 41943040);       // 8 MB

  float* outp = (float*)d_out;
  float* probs = outp + 4194304;

  convert_kernel<<<2048, 256, 0, stream>>>(x, w_qt, w_kt, w_qs, w_ks, w_v, w_o, xb, wcat, wob);
  gemm_qkv<<<dim3(32, 24), 256, 0, stream>>>(xb, wcat, qb, kb, vt);
  attn_kernel<<<dim3(64, 32), 256, 0, stream>>>(qb, kb, vt, amask, w_sigma, probs, ao);
  gemm_oproj<<<dim3(32, 8), 256, 0, stream>>>(ao, wob, outp);
}

// Round 6
// 310.591 us; speedup vs baseline: 1.3036x; 1.1219x over previous
//
#include <hip/hip_runtime.h>

typedef __bf16 bf16x8 __attribute__((ext_vector_type(8)));
typedef float f32x4 __attribute__((ext_vector_type(4)));
typedef float f32x16 __attribute__((ext_vector_type(16)));
typedef short short4v __attribute__((ext_vector_type(4)));
typedef unsigned short ushort8 __attribute__((ext_vector_type(8)));
typedef unsigned int uint4v __attribute__((ext_vector_type(4)));

#define AS1 __attribute__((address_space(1)))
#define AS3 __attribute__((address_space(3)))
#define GLL16(g, l) __builtin_amdgcn_global_load_lds((const AS1 void*)(g), (AS3 void*)(l), 16, 0, 0)
#define MFMA16(a, b, c) __builtin_amdgcn_mfma_f32_16x16x32_bf16((a), (b), (c), 0, 0, 0)
#define MFMA32(a, b, c) __builtin_amdgcn_mfma_f32_32x32x16_bf16((a), (b), (c), 0, 0, 0)
#define WAITVM(N) asm volatile("s_waitcnt vmcnt(" #N ")" ::: "memory")
#define WAITLGKM0 asm volatile("s_waitcnt lgkmcnt(0)" ::: "memory")
#define L2E 1.44269504f

__device__ __forceinline__ unsigned short f2bf(float f) {
  unsigned int u = __builtin_bit_cast(unsigned int, f);
  u = (u + 0x7fffu + ((u >> 16) & 1u)) >> 16;
  return (unsigned short)u;
}

__device__ __forceinline__ unsigned int cvtpk_bf16(float lo, float hi) {
  unsigned int r;
  asm("v_cvt_pk_bf16_f32 %0, %1, %2" : "=v"(r) : "v"(lo), "v"(hi));
  return r;
}

// ---------------- convert: f32 -> bf16 (x, concat weights, w_o) ----------------
__global__ void convert_kernel(const float* __restrict__ x,
                               const float* __restrict__ w_qt, const float* __restrict__ w_kt,
                               const float* __restrict__ w_qs, const float* __restrict__ w_ks,
                               const float* __restrict__ w_v, const float* __restrict__ w_o,
                               unsigned short* __restrict__ xb, unsigned short* __restrict__ wcat,
                               unsigned short* __restrict__ wob) {
  const int NX = 4096 * 1024, NW = 3072 * 1024, NO = 1024 * 1024;
  int stride = gridDim.x * blockDim.x;
  for (int i = blockIdx.x * blockDim.x + threadIdx.x; i < NX + NW + NO; i += stride) {
    if (i < NX) {
      xb[i] = f2bf(x[i]);
    } else if (i < NX + NW) {
      int j = i - NX;
      int n = j >> 10, k = j & 1023;
      const float* src;
      if (n < 256)        src = w_qt + n * 1024;
      else if (n < 1024)  src = w_qs + (n - 256) * 1024;
      else if (n < 1280)  src = w_kt + (n - 1024) * 1024;
      else if (n < 2048)  src = w_ks + (n - 1280) * 1024;
      else                src = w_v + (n - 2048) * 1024;
      wcat[j] = f2bf(src[k]);
    } else {
      int j = i - NX - NW;
      wob[j] = f2bf(w_o[j]);
    }
  }
}

// ---------------- GEMM 1: X(4096x1024) * Wcat(3072x1024)^T -> Q,K,Vt ----------------
__global__ __launch_bounds__(256) void gemm_qkv(const unsigned short* __restrict__ A,
                                                const unsigned short* __restrict__ Bw,
                                                unsigned short* __restrict__ qb,
                                                unsigned short* __restrict__ kb,
                                                unsigned short* __restrict__ vt) {
  __shared__ unsigned short As[128 * 32];
  __shared__ unsigned short Bs[128 * 32];
  const int t = threadIdx.x;
  const int lane = t & 63, wid = t >> 6;
  const int wm = wid >> 1, wn = wid & 1;
  const int lr = lane & 15, lg = lane >> 4;
  const int m0 = blockIdx.x * 128, n0 = blockIdx.y * 128;
  const int K = 1024;
  f32x4 acc[4][4] = {};
  const unsigned short* gA0 = A + (m0 + (t >> 2)) * K + (t & 3) * 8;
  const unsigned short* gB0 = Bw + (n0 + (t >> 2)) * K + (t & 3) * 8;
  char* lA = (char*)As + wid * 1024;
  char* lB = (char*)Bs + wid * 1024;
  for (int k0 = 0; k0 < K; k0 += 32) {
    __syncthreads();
    GLL16(gA0 + k0, lA);
    GLL16(gA0 + 64 * K + k0, lA + 4096);
    GLL16(gB0 + k0, lB);
    GLL16(gB0 + 64 * K + k0, lB + 4096);
    __syncthreads();
    bf16x8 af[4], bfr[4];
#pragma unroll
    for (int i = 0; i < 4; ++i) {
      af[i] = *(const bf16x8*)&As[(wm * 64 + i * 16 + lr) * 32 + lg * 8];
      bfr[i] = *(const bf16x8*)&Bs[(wn * 64 + i * 16 + lr) * 32 + lg * 8];
    }
#pragma unroll
    for (int i = 0; i < 4; ++i)
#pragma unroll
      for (int j = 0; j < 4; ++j)
        acc[i][j] = MFMA16(af[i], bfr[j], acc[i][j]);
  }
  // epilogue: scatter into Q (B,H,L,64), K (B,H,L,64), Vt (B,H,64,L)
#pragma unroll
  for (int i = 0; i < 4; ++i) {
#pragma unroll
    for (int j = 0; j < 4; ++j) {
      int n = n0 + wn * 64 + j * 16 + lr;
      int mb = m0 + wm * 64 + i * 16 + lg * 4;
      f32x4 v = acc[i][j];
      if (n < 2048) {
        unsigned short* dst = (n < 1024) ? qb : kb;
        int nn = n & 1023;
        int h = nn >> 6, d = nn & 63;
#pragma unroll
        for (int r = 0; r < 4; ++r) {
          int m = mb + r;
          int b = m >> 11, l = m & 2047;
          dst[((b * 16 + h) * 2048 + l) * 64 + d] = f2bf(v[r]);
        }
      } else {
        int nn = n - 2048;
        int h = nn >> 6, d = nn & 63;
        int b = mb >> 11, l = mb & 2047;
        short4v pk;
        pk[0] = (short)f2bf(v[0]); pk[1] = (short)f2bf(v[1]);
        pk[2] = (short)f2bf(v[2]); pk[3] = (short)f2bf(v[3]);
        *(short4v*)&vt[((b * 16 + h) * 64 + d) * 2048 + l] = pk;
      }
    }
  }
}

// ---------------- attention v6: LDS-staged K/V, x4 probs stores, per-wave pipeline ----------------
// Block = 32 q-rows of one bh; 4 waves, wave w owns k-slice [w*512, w*512+512).
// LDS per wave: K-tile 4KB (linear dest, src pre-swizzled), V-tile 4KB (interleaved d-layout),
// P-tile 4KB f32. pvacc aliases K region after the loop. No __syncthreads in k-loop.
__global__ __launch_bounds__(256, 3) void attn_kernel(const unsigned short* __restrict__ qb,
                                                      const unsigned short* __restrict__ kb,
                                                      const unsigned short* __restrict__ vt,
                                                      const float* __restrict__ mask,
                                                      const float* __restrict__ w_sigma,
                                                      float* __restrict__ probs,
                                                      unsigned short* __restrict__ ao) {
  __shared__ __align__(16) char smem[49792];
  const int t = threadIdx.x;
  const int lane = t & 63, w = t >> 6;
  const int col = lane & 31, hi = lane >> 5;
  const int srow = lane >> 3;                       // staging: row-in-group
  const int schunk = (lane & 7) ^ (srow & 7);       // staging: pre-swizzled chunk
  // XCD-chunked mapping: 8 consecutive-dispatch groups of 256 blocks each own 4 heads
  const int s = blockIdx.x;
  const int bh = (s & 7) * 4 + ((s >> 3) >> 6);
  const int q0 = ((s >> 3) & 63) * 32;
  const int b = bh >> 4, h = bh & 15;
  const float sigma = 1.0f / (1.0f + __expf(-w_sigma[0]));
  const float fac2 = ((h < 4) ? (-sigma * 0.125f) : 0.125f) * L2E;
  const float* maskb = mask + b * 2048;
  const int kbase = w * 512;

  char* Kl = smem + w * 4096;
  char* Vl = smem + 16384 + w * 4096;
  char* Pl = smem + 32768 + w * 4096;
  float (*psum)[32] = (float(*)[32])(smem + 49152);
  float* rsum = (float*)(smem + 49664);
  float* pvacc = (float*)smem;  // aliases K region; used only after loop + barrier

  const unsigned short* kb_bh = kb + (size_t)bh * 2048 * 64;
  const unsigned short* vt_bh = vt + (size_t)bh * 64 * 2048;

  // Q fragments (one-time gather)
  bf16x8 qf[4];
  {
    const unsigned short* qp = qb + (size_t)(bh * 2048 + q0 + col) * 64 + hi * 8;
#pragma unroll
    for (int m = 0; m < 4; ++m) qf[m] = *(const bf16x8*)(qp + m * 16);
  }

  // ---------------- pass 1: rowsums (K double-buffered across Kl/Vl) ----------------
#pragma unroll
  for (int j = 0; j < 4; ++j)
    GLL16(kb_bh + (size_t)(kbase + j * 8 + srow) * 64 + schunk * 8, Kl + j * 1024);
  float rs[16];
#pragma unroll
  for (int r = 0; r < 16; ++r) rs[r] = 0.f;
  for (int c = 0; c < 16; ++c) {
    int kc = kbase + c * 32;
    char* curb = (c & 1) ? Vl : Kl;
    char* nxtb = (c & 1) ? Kl : Vl;
    if (c < 15) {
#pragma unroll
      for (int j = 0; j < 4; ++j)
        GLL16(kb_bh + (size_t)(kc + 32 + j * 8 + srow) * 64 + schunk * 8, nxtb + j * 1024);
      WAITVM(4);
    } else {
      WAITVM(0);
    }
    f32x16 sacc = {};
#pragma unroll
    for (int m = 0; m < 4; ++m) {
      bf16x8 kf = *(const bf16x8*)(curb + col * 128 + (((2 * m + hi) ^ (col & 7)) << 4));
      sacc = MFMA32(qf[m], kf, sacc);
    }
    float mv2 = maskb[kc + col] * L2E;
#pragma unroll
    for (int r = 0; r < 16; ++r) rs[r] += exp2f(sacc[r] * fac2 + mv2);
  }
#pragma unroll
  for (int o = 1; o < 32; o <<= 1)
#pragma unroll
    for (int r = 0; r < 16; ++r) rs[r] += __shfl_xor(rs[r], o);
  if (col == 0) {
#pragma unroll
    for (int r = 0; r < 16; ++r) psum[w][(r & 3) + 8 * (r >> 2) + 4 * hi] = rs[r];
  }
  __syncthreads();
  if (t < 32) rsum[t] = -log2f(psum[0][t] + psum[1][t] + psum[2][t] + psum[3][t]);
  __syncthreads();

  float rws_l[16];
#pragma unroll
  for (int r = 0; r < 16; ++r) rws_l[r] = rsum[(r & 3) + 8 * (r >> 2) + 4 * hi];

  // ---------------- pass 2: probs stream + PV, single-buffered K & V ----------------
#pragma unroll
  for (int j = 0; j < 4; ++j)
    GLL16(kb_bh + (size_t)(kbase + j * 8 + srow) * 64 + schunk * 8, Kl + j * 1024);
#pragma unroll
  for (int j = 0; j < 4; ++j)
    GLL16(vt_bh + (size_t)(j * 8 + srow + (schunk >> 2) * 32) * 2048 + kbase + (schunk & 3) * 8,
          Vl + j * 1024);
  WAITVM(4);  // K(0) done, V(0) still in flight

  f32x16 oacc0 = {}, oacc1 = {};
  float* pp = probs + (size_t)(bh * 2048 + q0) * 2048;
  for (int c = 0; c < 16; ++c) {
    int kc = kbase + c * 32;
    WAITVM(8);  // K(c) landed (8 newer ops allowed: stores(c-1)x4 + V(c)x4)
    f32x16 sacc = {};
#pragma unroll
    for (int m = 0; m < 4; ++m) {
      bf16x8 kf = *(const bf16x8*)(Kl + col * 128 + (((2 * m + hi) ^ (col & 7)) << 4));
      sacc = MFMA32(qf[m], kf, sacc);
    }
    WAITLGKM0;  // K-frag reads retired; safe to overwrite Kl
    if (c < 15) {
#pragma unroll
      for (int j = 0; j < 4; ++j)
        GLL16(kb_bh + (size_t)(kc + 32 + j * 8 + srow) * 64 + schunk * 8, Kl + j * 1024);
    }
    float mv2 = maskb[kc + col] * L2E;
#pragma unroll
    for (int r = 0; r < 16; ++r) {
      float pv_ = exp2f(sacc[r] * fac2 + (rws_l[r] + mv2));
      int row = (r & 3) + 8 * (r >> 2) + 4 * hi;
      int off = (row * 128 + col * 4) ^ ((row & 7) << 4);
      *(float*)(Pl + off) = pv_;
    }
    // probs: 4x dwordx4 per lane, 8 rows x 128B per instr
#pragma unroll
    for (int j2 = 0; j2 < 4; ++j2) {
      int row = j2 * 8 + srow;
      f32x4 v = *(const f32x4*)(Pl + row * 128 + (schunk << 4));
      __builtin_nontemporal_store(v, (f32x4*)(pp + (size_t)row * 2048 + kc + (lane & 7) * 4));
    }
    // PV A-fragments from the same f32 tile
    uint4v u0, u1;
#pragma unroll
    for (int kh = 0; kh < 2; ++kh) {
      int cbase = kh * 4 + hi * 2;
      f32x4 a0 = *(const f32x4*)(Pl + col * 128 + (((cbase + 0) ^ (col & 7)) << 4));
      f32x4 a1 = *(const f32x4*)(Pl + col * 128 + (((cbase + 1) ^ (col & 7)) << 4));
      uint4v u;
      u[0] = cvtpk_bf16(a0[0], a0[1]); u[1] = cvtpk_bf16(a0[2], a0[3]);
      u[2] = cvtpk_bf16(a1[0], a1[1]); u[3] = cvtpk_bf16(a1[2], a1[3]);
      if (kh == 0) u0 = u; else u1 = u;
    }
    if (c < 15) { WAITVM(8); } else { WAITVM(4); }  // V(c) landed
#pragma unroll
    for (int kh = 0; kh < 2; ++kh) {
      bf16x8 pa = __builtin_bit_cast(bf16x8, kh == 0 ? u0 : u1);
#pragma unroll
      for (int dh = 0; dh < 2; ++dh) {
        bf16x8 vf = *(const bf16x8*)(Vl + col * 128 + (((dh * 4 + kh * 2 + hi) ^ (col & 7)) << 4));
        if (dh == 0) oacc0 = MFMA32(pa, vf, oacc0);
        else         oacc1 = MFMA32(pa, vf, oacc1);
      }
    }
    WAITLGKM0;  // V-frag reads retired; safe to overwrite Vl
    if (c < 15) {
#pragma unroll
      for (int j = 0; j < 4; ++j)
        GLL16(vt_bh + (size_t)(j * 8 + srow + (schunk >> 2) * 32) * 2048 + kc + 32 + (schunk & 3) * 8,
              Vl + j * 1024);
    }
  }

  // ---------------- merge PV partials (pvacc aliases Kl; all staging drained by barrier) ----------------
  __syncthreads();
  for (int i = t; i < 2048; i += 256) pvacc[i] = 0.0f;
  __syncthreads();
#pragma unroll
  for (int r = 0; r < 16; ++r) {
    int row = (r & 3) + 8 * (r >> 2) + 4 * hi;
    atomicAdd(&pvacc[row * 64 + col], oacc0[r]);
    atomicAdd(&pvacc[row * 64 + 32 + col], oacc1[r]);
  }
  __syncthreads();
  {
    int row = t >> 3, c8 = (t & 7) * 8;
    f32x4 v0 = *(const f32x4*)&pvacc[row * 64 + c8];
    f32x4 v1 = *(const f32x4*)&pvacc[row * 64 + c8 + 4];
    ushort8 o;
#pragma unroll
    for (int i = 0; i < 4; ++i) {
      o[i] = f2bf(v0[i]);
      o[i + 4] = f2bf(v1[i]);
    }
    *(ushort8*)&ao[((b * 2048) + q0 + row) * 1024 + h * 64 + c8] = o;
  }
}

// ---------------- GEMM 2: AO(4096x1024) * Wo(1024x1024)^T -> out f32 ----------------
__global__ __launch_bounds__(256) void gemm_oproj(const unsigned short* __restrict__ A,
                                                  const unsigned short* __restrict__ Bw,
                                                  float* __restrict__ out) {
  __shared__ unsigned short As[128 * 32];
  __shared__ unsigned short Bs[128 * 32];
  const int t = threadIdx.x;
  const int lane = t & 63, wid = t >> 6;
  const int wm = wid >> 1, wn = wid & 1;
  const int lr = lane & 15, lg = lane >> 4;
  const int m0 = blockIdx.x * 128, n0 = blockIdx.y * 128;
  const int K = 1024;
  f32x4 acc[4][4] = {};
  const unsigned short* gA0 = A + (m0 + (t >> 2)) * K + (t & 3) * 8;
  const unsigned short* gB0 = Bw + (n0 + (t >> 2)) * K + (t & 3) * 8;
  char* lA = (char*)As + wid * 1024;
  char* lB = (char*)Bs + wid * 1024;
  for (int k0 = 0; k0 < K; k0 += 32) {
    __syncthreads();
    GLL16(gA0 + k0, lA);
    GLL16(gA0 + 64 * K + k0, lA + 4096);
    GLL16(gB0 + k0, lB);
    GLL16(gB0 + 64 * K + k0, lB + 4096);
    __syncthreads();
    bf16x8 af[4], bfr[4];
#pragma unroll
    for (int i = 0; i < 4; ++i) {
      af[i] = *(const bf16x8*)&As[(wm * 64 + i * 16 + lr) * 32 + lg * 8];
      bfr[i] = *(const bf16x8*)&Bs[(wn * 64 + i * 16 + lr) * 32 + lg * 8];
    }
#pragma unroll
    for (int i = 0; i < 4; ++i)
#pragma unroll
      for (int j = 0; j < 4; ++j)
        acc[i][j] = MFMA16(af[i], bfr[j], acc[i][j]);
  }
#pragma unroll
  for (int i = 0; i < 4; ++i) {
#pragma unroll
    for (int j = 0; j < 4; ++j) {
      int n = n0 + wn * 64 + j * 16 + lr;
      int mb = m0 + wm * 64 + i * 16 + lg * 4;
#pragma unroll
      for (int r = 0; r < 4; ++r)
        out[(mb + r) * 1024 + n] = acc[i][j][r];
    }
  }
}

extern "C" void kernel_launch(void* const* d_in, const int* in_sizes, int n_in,
                              void* d_out, int out_size, void* d_ws, size_t ws_size,
                              hipStream_t stream) {
  const float* x       = (const float*)d_in[0];
  const float* amask   = (const float*)d_in[1];
  const float* w_qt    = (const float*)d_in[2];
  const float* w_kt    = (const float*)d_in[3];
  const float* w_qs    = (const float*)d_in[4];
  const float* w_ks    = (const float*)d_in[5];
  const float* w_sigma = (const float*)d_in[6];
  const float* w_v     = (const float*)d_in[7];
  const float* w_o     = (const float*)d_in[8];

  char* ws = (char*)d_ws;
  unsigned short* xb   = (unsigned short*)ws;                    // 8 MB
  unsigned short* wcat = (unsigned short*)(ws + 8388608);        // 6 MB
  unsigned short* wob  = (unsigned short*)(ws + 14680064);       // 2 MB
  unsigned short* qb   = (unsigned short*)(ws + 16777216);       // 8 MB
  unsigned short* kb   = (unsigned short*)(ws + 25165824);       // 8 MB
  unsigned short* vt   = (unsigned short*)(ws + 33554432);       // 8 MB
  unsigned short* ao   = (unsigned short*)(ws + 41943040);       // 8 MB

  float* outp = (float*)d_out;
  float* probs = outp + 4194304;

  convert_kernel<<<2048, 256, 0, stream>>>(x, w_qt, w_kt, w_qs, w_ks, w_v, w_o, xb, wcat, wob);
  gemm_qkv<<<dim3(32, 24), 256, 0, stream>>>(xb, wcat, qb, kb, vt);
  attn_kernel<<<2048, 256, 0, stream>>>(qb, kb, vt, amask, w_sigma, probs, ao);
  gemm_oproj<<<dim3(32, 8), 256, 0, stream>>>(ao, wob, outp);
}